// Round 5
// baseline (980.325 us; speedup 1.0000x reference)
//
#include <hip/hip_runtime.h>
#include <stdint.h>
#include <math.h>

#define Bn   4096
#define Dn   2048
#define Hn   8
#define HSn  256
#define Pn   2730
#define PPADn 2816
#define EPSn 1e-5f

using f32x4  = __attribute__((ext_vector_type(4))) float;
using bf16x8 = __attribute__((ext_vector_type(8))) short;
using u16x4  = __attribute__((ext_vector_type(4))) unsigned short;

__device__ __forceinline__ unsigned short f2bf(float f) {
  union { float f; uint32_t u; } x; x.f = f;
  uint32_t u = x.u;
  return (unsigned short)((u + 0x7FFFu + ((u >> 16) & 1u)) >> 16);
}

// XCD-aware bijective swizzle (valid when n % 8 == 0): consecutive tiles on one XCD
__device__ __forceinline__ int xcd_swz(int bid, int n) {
  return (bid & 7) * (n >> 3) + (bid >> 3);
}

// global -> LDS direct (16B per lane). LDS dest must be wave-uniform.
#define GLDS(gp, lp) __builtin_amdgcn_global_load_lds(                        \
    (__attribute__((address_space(1))) void*)(size_t)(gp),                    \
    (__attribute__((address_space(3))) void*)(lp), 16, 0, 0)

// ---------------------------------------------------------------------------
// 128x128 tile, BK=64, 4 waves (2x2 of 64x64), mfma_f32_16x16x32_bf16.
// Double-buffered 2-phase pipeline: stage(t+1) issued BEFORE compute(t); the
// single __syncthreads() per K-step drains vmcnt AFTER compute, hiding latency.
// A: [M][K] row-major bf16 (lda), Bt: [N][K] row-major bf16 (ldb). nk must be even.
// ---------------------------------------------------------------------------
__device__ __forceinline__ void stage_tile(
    const ushort* __restrict__ A, int lda,
    const ushort* __restrict__ Bt, int ldb,
    int row0, int col0, int kt,
    ushort* Asm, ushort* Bsm, int tid, int wid)
{
  #pragma unroll
  for (int q = 0; q < 4; ++q) {
    int ee = q * 256 + tid;              // element = 8 bf16 (16B)
    int r = ee >> 3, c = (ee & 7) << 3;
    GLDS(A  + (size_t)(row0 + r) * lda + (size_t)kt * 64 + c,
         (char*)Asm + (q * 4096 + wid * 1024));
    GLDS(Bt + (size_t)(col0 + r) * ldb + (size_t)kt * 64 + c,
         (char*)Bsm + (q * 4096 + wid * 1024));
  }
}

__device__ __forceinline__ void compute_tile(
    const ushort* Asm, const ushort* Bsm, f32x4 acc[4][4],
    int l16, int lhi, int wm, int wn)
{
  #pragma unroll
  for (int kk = 0; kk < 2; ++kk) {
    bf16x8 af[4], bfr[4];
    #pragma unroll
    for (int i = 0; i < 4; ++i) {
      af[i]  = *(const bf16x8*)(Asm + (wm + i * 16 + l16) * 64 + kk * 32 + lhi * 8);
      bfr[i] = *(const bf16x8*)(Bsm + (wn + i * 16 + l16) * 64 + kk * 32 + lhi * 8);
    }
    #pragma unroll
    for (int i = 0; i < 4; ++i)
      #pragma unroll
      for (int j = 0; j < 4; ++j)
        acc[i][j] = __builtin_amdgcn_mfma_f32_16x16x32_bf16(af[i], bfr[j], acc[i][j], 0, 0, 0);
  }
}

__device__ __forceinline__ void gemm_mainloop_db(
    const ushort* __restrict__ A, int lda,
    const ushort* __restrict__ Bt, int ldb,
    int K, int row0, int col0,
    ushort* Asm0, ushort* Bsm0, ushort* Asm1, ushort* Bsm1,
    f32x4 acc[4][4])
{
  const int tid  = threadIdx.x;
  const int wid  = tid >> 6;
  const int lane = tid & 63;
  const int l16  = lane & 15, lhi = lane >> 4;
  const int wm   = (wid >> 1) * 64, wn = (wid & 1) * 64;
  const int nk   = K >> 6;                     // must be even

  stage_tile(A, lda, Bt, ldb, row0, col0, 0, Asm0, Bsm0, tid, wid);
  __syncthreads();                             // first tile resident
  for (int kt = 0; kt < nk; kt += 2) {
    // phase A: prefetch kt+1 into buf1, compute kt from buf0
    stage_tile(A, lda, Bt, ldb, row0, col0, kt + 1, Asm1, Bsm1, tid, wid);
    compute_tile(Asm0, Bsm0, acc, l16, lhi, wm, wn);
    __syncthreads();                           // drains prefetch (hidden under compute)
    // phase B: prefetch kt+2 into buf0, compute kt+1 from buf1
    if (kt + 2 < nk)
      stage_tile(A, lda, Bt, ldb, row0, col0, kt + 2, Asm0, Bsm0, tid, wid);
    compute_tile(Asm1, Bsm1, acc, l16, lhi, wm, wn);
    __syncthreads();
  }
}

// ---------------------------------------------------------------------------
// Weight conversion: generic f32 [R][C] -> bf16 [Cpad][Rpad] (B^T), zero pad.
// ---------------------------------------------------------------------------
__global__ void transpose_cvt_kernel(const float* __restrict__ in, ushort* __restrict__ out,
                                     int R, int C, int Rpad, int Cpad)
{
  __shared__ float tile[32][33];
  int r0 = blockIdx.y * 32, c0 = blockIdx.x * 32;
  int tx = threadIdx.x, ty = threadIdx.y;
  #pragma unroll
  for (int i = 0; i < 32; i += 8) {
    int r = r0 + ty + i, c = c0 + tx;
    tile[ty + i][tx] = (r < R && c < C) ? in[(size_t)r * C + c] : 0.f;
  }
  __syncthreads();
  #pragma unroll
  for (int i = 0; i < 32; i += 8) {
    int cc = c0 + ty + i, rr = r0 + tx;
    if (cc < Cpad && rr < Rpad)
      out[(size_t)cc * Rpad + rr] = f2bf(tile[tx][ty + i]);
  }
}

struct Ptr8 { const float* p[8]; };

// gate weights: 8 tensors (Wz,Wi,Wf,Wo,Rz,Ri,Rf,Ro), each [H][256][256] ->
// out[(tensor*8+h)][o][i] bf16 (per-head transpose)
__global__ void gate_wcvt_kernel(Ptr8 src, ushort* __restrict__ out)
{
  __shared__ float tile[32][33];
  int tz = blockIdx.z;                 // 0..63
  int tensor = tz >> 3, h = tz & 7;
  const float* in = src.p[tensor] + (size_t)h * HSn * HSn;
  ushort* o = out + (size_t)tz * HSn * HSn;
  int r0 = blockIdx.y * 32, c0 = blockIdx.x * 32;
  int tx = threadIdx.x, ty = threadIdx.y;
  #pragma unroll
  for (int i = 0; i < 32; i += 8)
    tile[ty + i][tx] = in[(size_t)(r0 + ty + i) * HSn + c0 + tx];
  __syncthreads();
  #pragma unroll
  for (int i = 0; i < 32; i += 8)
    o[(size_t)(c0 + ty + i) * HSn + (r0 + tx)] = f2bf(tile[tx][ty + i]);
}

__global__ void cvt_bf16_kernel(const float* __restrict__ in, ushort* __restrict__ out, int n8)
{
  int idx = blockIdx.x * blockDim.x + threadIdx.x;
  if (idx >= n8) return;
  float4 a = ((const float4*)in)[idx * 2];
  float4 b = ((const float4*)in)[idx * 2 + 1];
  bf16x8 v;
  v[0] = (short)f2bf(a.x); v[1] = (short)f2bf(a.y);
  v[2] = (short)f2bf(a.z); v[3] = (short)f2bf(a.w);
  v[4] = (short)f2bf(b.x); v[5] = (short)f2bf(b.y);
  v[6] = (short)f2bf(b.z); v[7] = (short)f2bf(b.w);
  ((bf16x8*)out)[idx] = v;
}

// ---------------------------------------------------------------------------
// LayerNorm + causal conv1d(k=4) + SiLU, per row. Emits x (bf16) and x_conv (bf16).
// ---------------------------------------------------------------------------
__global__ __launch_bounds__(256) void ln_conv_kernel(
    const float* __restrict__ x, const float* __restrict__ lnw, const float* __restrict__ lnb,
    const float* __restrict__ convw, const float* __restrict__ convb,
    ushort* __restrict__ xbf, ushort* __restrict__ xcbf)
{
  __shared__ float xn[Dn];
  __shared__ float red[8];
  const int b = blockIdx.x, t = threadIdx.x;
  const float* xr = x + (size_t)b * Dn;
  float4 v0 = ((const float4*)xr)[t * 2];
  float4 v1 = ((const float4*)xr)[t * 2 + 1];
  float xv[8] = {v0.x, v0.y, v0.z, v0.w, v1.x, v1.y, v1.z, v1.w};
  float s = 0.f, s2 = 0.f;
  #pragma unroll
  for (int e = 0; e < 8; ++e) { s += xv[e]; s2 += xv[e] * xv[e]; }
  #pragma unroll
  for (int off = 32; off >= 1; off >>= 1) {
    s  += __shfl_xor(s, off, 64);
    s2 += __shfl_xor(s2, off, 64);
  }
  int wid = t >> 6;
  if ((t & 63) == 0) { red[wid] = s; red[4 + wid] = s2; }
  __syncthreads();
  s  = red[0] + red[1] + red[2] + red[3];
  s2 = red[4] + red[5] + red[6] + red[7];
  float mean = s * (1.f / Dn);
  float var  = s2 * (1.f / Dn) - mean * mean;
  float rstd = rsqrtf(var + EPSn);

  float4 w0 = ((const float4*)lnw)[t * 2], w1 = ((const float4*)lnw)[t * 2 + 1];
  float4 b0 = ((const float4*)lnb)[t * 2], b1 = ((const float4*)lnb)[t * 2 + 1];
  float lw[8] = {w0.x, w0.y, w0.z, w0.w, w1.x, w1.y, w1.z, w1.w};
  float lb[8] = {b0.x, b0.y, b0.z, b0.w, b1.x, b1.y, b1.z, b1.w};
  bf16x8 xb;
  #pragma unroll
  for (int e = 0; e < 8; ++e) {
    int j = t * 8 + e;
    float nv = (xv[e] - mean) * rstd * lw[e] + lb[e];
    xn[j] = nv;
    xb[e] = (short)f2bf(xv[e]);
  }
  ((bf16x8*)(xbf + (size_t)b * Dn))[t] = xb;
  __syncthreads();
  float w[4] = {convw[0], convw[1], convw[2], convw[3]};
  float cb = convb[0];
  bf16x8 cv;
  #pragma unroll
  for (int e = 0; e < 8; ++e) {
    int j = t * 8 + e;
    float a0 = (j >= 3) ? xn[j - 3] : 0.f;
    float a1 = (j >= 2) ? xn[j - 2] : 0.f;
    float a2 = (j >= 1) ? xn[j - 1] : 0.f;
    float v = w[0] * a0 + w[1] * a1 + w[2] * a2 + w[3] * xn[j] + cb;
    float sv = v / (1.f + expf(-v));
    cv[e] = (short)f2bf(sv);
  }
  ((bf16x8*)(xcbf + (size_t)b * Dn))[t] = cv;
}

// ---------------------------------------------------------------------------
// Gate GEMMs: grid (64 tiles, 8 heads, 4 gates). gate 0=z,1=i,2=f,3=o.
// C = A1@W^T + A2@R^T; A1 = x (z,o) or x_conv (i,f); A2 = h_prev.
// ---------------------------------------------------------------------------
struct GateArgs { const float* wb[4]; const float* rb[4]; };

__global__ __launch_bounds__(256) void gate_gemm_kernel(
    const ushort* __restrict__ xbf, const ushort* __restrict__ xcbf,
    const ushort* __restrict__ hbf, const ushort* __restrict__ gWt,
    GateArgs gb, float* __restrict__ preact)
{
  __shared__ ushort Asm0[128 * 64], Bsm0[128 * 64];
  __shared__ ushort Asm1[128 * 64], Bsm1[128 * 64];
  const int g = blockIdx.z, h = blockIdx.y;
  const int bx = xcd_swz(blockIdx.x, 64);
  const int mt = bx >> 1, nt = bx & 1;
  const int row0 = mt * 128, col0 = nt * 128;
  f32x4 acc[4][4];
  #pragma unroll
  for (int i = 0; i < 4; ++i)
    #pragma unroll
    for (int j = 0; j < 4; ++j) acc[i][j] = f32x4{0.f, 0.f, 0.f, 0.f};

  const ushort* A1 = ((g == 1 || g == 2) ? xcbf : xbf) + h * HSn;
  const ushort* B1 = gWt + (size_t)(g * 8 + h) * (HSn * HSn);
  gemm_mainloop_db(A1, Dn, B1, HSn, HSn, row0, col0, Asm0, Bsm0, Asm1, Bsm1, acc);
  const ushort* A2 = hbf + h * HSn;
  const ushort* B2 = gWt + (size_t)((4 + g) * 8 + h) * (HSn * HSn);
  gemm_mainloop_db(A2, Dn, B2, HSn, HSn, row0, col0, Asm0, Bsm0, Asm1, Bsm1, acc);

  const int tid = threadIdx.x, wid = tid >> 6, lane = tid & 63;
  const int l16 = lane & 15, lhi = lane >> 4;
  const int wm = (wid >> 1) * 64, wn = (wid & 1) * 64;
  float* out = preact + (size_t)g * ((size_t)Bn * Dn);
  const float* wb = gb.wb[g] + h * HSn;
  const float* rb = gb.rb[g] + h * HSn;
  #pragma unroll
  for (int j = 0; j < 4; ++j) {
    int cg = col0 + wn + j * 16 + l16;            // 0..255 within head
    float bias = wb[cg] + rb[cg];
    #pragma unroll
    for (int i = 0; i < 4; ++i) {
      #pragma unroll
      for (int r = 0; r < 4; ++r) {
        int rg = row0 + wm + i * 16 + lhi * 4 + r;
        float v = acc[i][j][r] + bias;
        if (g == 0) v = tanhf(v);
        else if (g == 3) v = 1.f / (1.f + expf(-v));
        out[(size_t)rg * Dn + h * HSn + cg] = v;
      }
    }
  }
}

// ---------------------------------------------------------------------------
// exp-gating pointwise + GroupNorm(8 groups of 256). 1 wave per (b, head).
// ---------------------------------------------------------------------------
__global__ __launch_bounds__(64) void gate_pw_gn_kernel(
    const float* __restrict__ preact,
    const float* __restrict__ c_prev, const float* __restrict__ n_prev,
    const float* __restrict__ m_prev,
    const float* __restrict__ gn_w, const float* __restrict__ gn_b,
    float* __restrict__ o_h, float* __restrict__ o_c,
    float* __restrict__ o_n, float* __restrict__ o_m,
    ushort* __restrict__ gnbf)
{
  const int bh = blockIdx.x;
  const int b = bh >> 3, h = bh & 7;
  const int t = threadIdx.x;
  const size_t NE = (size_t)Bn * Dn;
  const size_t base = (size_t)b * Dn + h * HSn + t * 4;

  float4 z4 = *(const float4*)(preact + base);
  float4 i4 = *(const float4*)(preact + NE + base);
  float4 f4 = *(const float4*)(preact + 2 * NE + base);
  float4 o4 = *(const float4*)(preact + 3 * NE + base);
  float4 c4 = *(const float4*)(c_prev + base);
  float4 n4 = *(const float4*)(n_prev + base);
  float4 m4 = *(const float4*)(m_prev + base);

  float za[4] = {z4.x, z4.y, z4.z, z4.w};
  float ia[4] = {i4.x, i4.y, i4.z, i4.w};
  float fa[4] = {f4.x, f4.y, f4.z, f4.w};
  float oa[4] = {o4.x, o4.y, o4.z, o4.w};
  float ca[4] = {c4.x, c4.y, c4.z, c4.w};
  float na[4] = {n4.x, n4.y, n4.z, n4.w};
  float ma[4] = {m4.x, m4.y, m4.z, m4.w};

  float hv[4], mo[4], co[4], no[4];
  float s = 0.f, s2 = 0.f;
  #pragma unroll
  for (int e = 0; e < 4; ++e) {
    float mt = fmaxf(fa[e] + ma[e], ia[e]);
    float ig = expf(ia[e] - mt);
    float fg = expf(fa[e] + ma[e] - mt);
    float ct = fg * ca[e] + ig * za[e];
    float nt = fg * na[e] + ig;
    float ht = oa[e] * ct / nt;
    mo[e] = mt; co[e] = ct; no[e] = nt; hv[e] = ht;
    s += ht; s2 += ht * ht;
  }
  *(float4*)(o_m + base) = make_float4(mo[0], mo[1], mo[2], mo[3]);
  *(float4*)(o_c + base) = make_float4(co[0], co[1], co[2], co[3]);
  *(float4*)(o_n + base) = make_float4(no[0], no[1], no[2], no[3]);
  *(float4*)(o_h + base) = make_float4(hv[0], hv[1], hv[2], hv[3]);

  #pragma unroll
  for (int off = 32; off >= 1; off >>= 1) {
    s  += __shfl_xor(s, off, 64);
    s2 += __shfl_xor(s2, off, 64);
  }
  float mean = s * (1.f / HSn);
  float var  = s2 * (1.f / HSn) - mean * mean;
  float rstd = rsqrtf(var + EPSn);
  u16x4 gv;
  #pragma unroll
  for (int e = 0; e < 4; ++e) {
    int hid = h * HSn + t * 4 + e;
    float gval = (hv[e] - mean) * rstd * gn_w[hid] + gn_b[hid];
    gv[e] = f2bf(gval);
  }
  *(u16x4*)(gnbf + base) = gv;
}

// ---------------------------------------------------------------------------
// up GEMM (mode 0: store left f32; mode 1: act = left * gelu(right) -> bf16)
// ---------------------------------------------------------------------------
__global__ __launch_bounds__(256) void up_gemm_kernel(
    const ushort* __restrict__ gnbf, const ushort* __restrict__ upt,
    const float* __restrict__ upb, float* __restrict__ leftbuf,
    ushort* __restrict__ actbf, int mode)
{
  __shared__ ushort Asm0[128 * 64], Bsm0[128 * 64];
  __shared__ ushort Asm1[128 * 64], Bsm1[128 * 64];
  const int NT = PPADn / 128;                  // 22
  const int bx = xcd_swz(blockIdx.x, 32 * NT);
  const int mt = bx / NT, nt = bx % NT;
  const int row0 = mt * 128, col0 = nt * 128;
  f32x4 acc[4][4];
  #pragma unroll
  for (int i = 0; i < 4; ++i)
    #pragma unroll
    for (int j = 0; j < 4; ++j) acc[i][j] = f32x4{0.f, 0.f, 0.f, 0.f};

  gemm_mainloop_db(gnbf, Dn, upt, Dn, Dn, row0, col0, Asm0, Bsm0, Asm1, Bsm1, acc);

  const int tid = threadIdx.x, wid = tid >> 6, lane = tid & 63;
  const int l16 = lane & 15, lhi = lane >> 4;
  const int wm = (wid >> 1) * 64, wn = (wid & 1) * 64;
  #pragma unroll
  for (int j = 0; j < 4; ++j) {
    int col = col0 + wn + j * 16 + l16;
    float bias = (col < Pn) ? upb[col] : 0.f;
    #pragma unroll
    for (int i = 0; i < 4; ++i) {
      #pragma unroll
      for (int r = 0; r < 4; ++r) {
        int rg = row0 + wm + i * 16 + lhi * 4 + r;
        float v = acc[i][j][r] + bias;
        size_t idx = (size_t)rg * PPADn + col;
        if (mode == 0) {
          leftbuf[idx] = v;
        } else {
          float ge = 0.5f * v * (1.f + erff(v * 0.70710678118f));
          actbf[idx] = f2bf(leftbuf[idx] * ge);
        }
      }
    }
  }
}

// ---------------------------------------------------------------------------
// down GEMM: out = act @ down + bias + x
// ---------------------------------------------------------------------------
__global__ __launch_bounds__(256) void down_gemm_kernel(
    const ushort* __restrict__ actbf, const ushort* __restrict__ downt,
    const float* __restrict__ downb, const float* __restrict__ x,
    float* __restrict__ outp)
{
  __shared__ ushort Asm0[128 * 64], Bsm0[128 * 64];
  __shared__ ushort Asm1[128 * 64], Bsm1[128 * 64];
  const int NT = Dn / 128;                     // 16
  const int bx = xcd_swz(blockIdx.x, 32 * NT);
  const int mt = bx / NT, nt = bx % NT;
  const int row0 = mt * 128, col0 = nt * 128;
  f32x4 acc[4][4];
  #pragma unroll
  for (int i = 0; i < 4; ++i)
    #pragma unroll
    for (int j = 0; j < 4; ++j) acc[i][j] = f32x4{0.f, 0.f, 0.f, 0.f};

  gemm_mainloop_db(actbf, PPADn, downt, PPADn, PPADn, row0, col0, Asm0, Bsm0, Asm1, Bsm1, acc);

  const int tid = threadIdx.x, wid = tid >> 6, lane = tid & 63;
  const int l16 = lane & 15, lhi = lane >> 4;
  const int wm = (wid >> 1) * 64, wn = (wid & 1) * 64;
  #pragma unroll
  for (int j = 0; j < 4; ++j) {
    int col = col0 + wn + j * 16 + l16;
    float bias = downb[col];
    #pragma unroll
    for (int i = 0; i < 4; ++i) {
      #pragma unroll
      for (int r = 0; r < 4; ++r) {
        int rg = row0 + wm + i * 16 + lhi * 4 + r;
        size_t idx = (size_t)rg * Dn + col;
        outp[idx] = acc[i][j][r] + bias + x[idx];
      }
    }
  }
}

// ---------------------------------------------------------------------------
extern "C" void kernel_launch(void* const* d_in, const int* in_sizes, int n_in,
                              void* d_out, int out_size, void* d_ws, size_t ws_size,
                              hipStream_t stream)
{
  const float* x      = (const float*)d_in[0];
  const float* h_prev = (const float*)d_in[1];
  const float* c_prev = (const float*)d_in[2];
  const float* n_prev = (const float*)d_in[3];
  const float* m_prev = (const float*)d_in[4];
  const float* ln_w   = (const float*)d_in[5];
  const float* ln_b   = (const float*)d_in[6];
  const float* conv_w = (const float*)d_in[7];
  const float* conv_b = (const float*)d_in[8];
  const float* gn_w   = (const float*)d_in[9];
  const float* gn_b   = (const float*)d_in[10];
  const float* upL_w  = (const float*)d_in[11];
  const float* upL_b  = (const float*)d_in[12];
  const float* upR_w  = (const float*)d_in[13];
  const float* upR_b  = (const float*)d_in[14];
  const float* down_w = (const float*)d_in[15];
  const float* down_b = (const float*)d_in[16];

  const size_t NE = (size_t)Bn * Dn;

  // workspace layout. leftbuf/actbf ALIAS the preact region (preact is fully
  // consumed by gate_pw_gn before up_gemm writes leftbuf; stream order
  // serializes). Peak ws use ~235 MB.
  char* ws = (char*)d_ws;
  size_t off = 0;
  auto alloc = [&](size_t bytes) { void* p = ws + off; off += (bytes + 255) & ~(size_t)255; return p; };
  ushort* xbf   = (ushort*)alloc(NE * 2);
  ushort* xcbf  = (ushort*)alloc(NE * 2);
  ushort* hbf   = (ushort*)alloc(NE * 2);
  ushort* gnbf  = (ushort*)alloc(NE * 2);
  ushort* gWt   = (ushort*)alloc((size_t)8 * Hn * HSn * HSn * 2);
  ushort* upLt  = (ushort*)alloc((size_t)PPADn * Dn * 2);
  ushort* upRt  = (ushort*)alloc((size_t)PPADn * Dn * 2);
  ushort* downt = (ushort*)alloc((size_t)Dn * PPADn * 2);
  float*  preact  = (float*)alloc(4 * NE * 4);          // 128 MB
  float*  leftbuf = (float*)preact;                     // 46 MB (alias)
  ushort* actbf   = (ushort*)(preact + (size_t)Bn * PPADn);  // 23 MB (alias)
  (void)ws_size; (void)in_sizes; (void)n_in; (void)out_size;

  float* out = (float*)d_out;
  float* o_out = out;
  float* o_h = out + NE;
  float* o_c = out + 2 * NE;
  float* o_n = out + 3 * NE;
  float* o_m = out + 4 * NE;

  // 1. gate weight transpose-convert (8 tensors x 8 heads)
  Ptr8 src;
  src.p[0] = (const float*)d_in[17]; src.p[1] = (const float*)d_in[19];
  src.p[2] = (const float*)d_in[21]; src.p[3] = (const float*)d_in[23];
  src.p[4] = (const float*)d_in[25]; src.p[5] = (const float*)d_in[27];
  src.p[6] = (const float*)d_in[29]; src.p[7] = (const float*)d_in[31];
  gate_wcvt_kernel<<<dim3(8, 8, 64), dim3(32, 8), 0, stream>>>(src, gWt);

  // 2. MLP weight transposes (B^T layout, P padded to 2816 with zeros)
  transpose_cvt_kernel<<<dim3(PPADn / 32, Dn / 32), dim3(32, 8), 0, stream>>>(
      upL_w, upLt, Dn, Pn, Dn, PPADn);
  transpose_cvt_kernel<<<dim3(PPADn / 32, Dn / 32), dim3(32, 8), 0, stream>>>(
      upR_w, upRt, Dn, Pn, Dn, PPADn);
  transpose_cvt_kernel<<<dim3(Dn / 32, PPADn / 32), dim3(32, 8), 0, stream>>>(
      down_w, downt, Pn, Dn, PPADn, Dn);

  // 3. h_prev -> bf16
  cvt_bf16_kernel<<<(int)(NE / 8 / 256), 256, 0, stream>>>(h_prev, hbf, (int)(NE / 8));

  // 4. LayerNorm + conv + silu (also emits x as bf16)
  ln_conv_kernel<<<Bn, 256, 0, stream>>>(x, ln_w, ln_b, conv_w, conv_b, xbf, xcbf);

  // 5. gate GEMMs
  GateArgs ga;
  ga.wb[0] = (const float*)d_in[18]; ga.wb[1] = (const float*)d_in[20];
  ga.wb[2] = (const float*)d_in[22]; ga.wb[3] = (const float*)d_in[24];
  ga.rb[0] = (const float*)d_in[26]; ga.rb[1] = (const float*)d_in[28];
  ga.rb[2] = (const float*)d_in[30]; ga.rb[3] = (const float*)d_in[32];
  gate_gemm_kernel<<<dim3(64, 8, 4), 256, 0, stream>>>(xbf, xcbf, hbf, gWt, ga, preact);

  // 6. gating pointwise + GroupNorm
  gate_pw_gn_kernel<<<Bn * Hn, 64, 0, stream>>>(preact, c_prev, n_prev, m_prev,
                                                gn_w, gn_b, o_h, o_c, o_n, o_m, gnbf);

  // 7/8. up GEMMs (left, then right fused with gelu-gate -> act bf16)
  up_gemm_kernel<<<32 * (PPADn / 128), 256, 0, stream>>>(gnbf, upLt, upL_b, leftbuf, actbf, 0);
  up_gemm_kernel<<<32 * (PPADn / 128), 256, 0, stream>>>(gnbf, upRt, upR_b, leftbuf, actbf, 1);

  // 9. down GEMM + bias + residual
  down_gemm_kernel<<<32 * (Dn / 128), 256, 0, stream>>>(actbf, downt, down_b, x, o_out);
}

// Round 9
// 813.789 us; speedup vs baseline: 1.2046x; 1.2046x over previous
//
#include <hip/hip_runtime.h>
#include <stdint.h>
#include <math.h>

#define Bn   4096
#define Dn   2048
#define Hn   8
#define HSn  256
#define Pn   2730
#define PPADn 2816
#define EPSn 1e-5f

using f32x4  = __attribute__((ext_vector_type(4))) float;
using bf16x8 = __attribute__((ext_vector_type(8))) short;
using u16x4  = __attribute__((ext_vector_type(4))) unsigned short;

__device__ __forceinline__ unsigned short f2bf(float f) {
  union { float f; uint32_t u; } x; x.f = f;
  uint32_t u = x.u;
  return (unsigned short)((u + 0x7FFFu + ((u >> 16) & 1u)) >> 16);
}

// XCD-aware bijective swizzle (valid when n % 8 == 0)
__device__ __forceinline__ int xcd_swz(int bid, int n) {
  return (bid & 7) * (n >> 3) + (bid >> 3);
}

// global -> LDS direct (16B per lane). LDS dest must be wave-uniform.
#define GLDS(gp, lp) __builtin_amdgcn_global_load_lds(                        \
    (__attribute__((address_space(1))) void*)(size_t)(gp),                    \
    (__attribute__((address_space(3))) void*)(lp), 16, 0, 0)

// ---------------------------------------------------------------------------
// Single-B 128x128 tile mainloop (m97 structure, 2 barriers/K-step).
// A: [M][K] bf16 row-major (lda), Bt: [N][K] bf16 row-major (ldb).
// ---------------------------------------------------------------------------
__device__ __forceinline__ void gemm_mainloop(
    const ushort* __restrict__ A, int lda,
    const ushort* __restrict__ Bt, int ldb,
    int K, int row0, int col0,
    ushort* Asm, ushort* Bsm, f32x4 acc[4][4])
{
  const int tid  = threadIdx.x;
  const int wid  = tid >> 6;
  const int lane = tid & 63;
  const int l16  = lane & 15, lhi = lane >> 4;
  const int wm   = (wid >> 1) * 64, wn = (wid & 1) * 64;
  const int nk   = K >> 6;

  for (int kt = 0; kt < nk; ++kt) {
    __syncthreads();
    #pragma unroll
    for (int q = 0; q < 4; ++q) {
      int ee = q * 256 + tid;
      int r = ee >> 3, c = (ee & 7) << 3;
      GLDS(A  + (size_t)(row0 + r) * lda + (size_t)kt * 64 + c,
           (char*)Asm + (q * 4096 + wid * 1024));
      GLDS(Bt + (size_t)(col0 + r) * ldb + (size_t)kt * 64 + c,
           (char*)Bsm + (q * 4096 + wid * 1024));
    }
    __syncthreads();
    #pragma unroll
    for (int kk = 0; kk < 2; ++kk) {
      bf16x8 af[4], bfr[4];
      #pragma unroll
      for (int i = 0; i < 4; ++i) {
        af[i]  = *(const bf16x8*)(Asm + (wm + i * 16 + l16) * 64 + kk * 32 + lhi * 8);
        bfr[i] = *(const bf16x8*)(Bsm + (wn + i * 16 + l16) * 64 + kk * 32 + lhi * 8);
      }
      #pragma unroll
      for (int i = 0; i < 4; ++i)
        #pragma unroll
        for (int j = 0; j < 4; ++j)
          acc[i][j] = __builtin_amdgcn_mfma_f32_16x16x32_bf16(af[i], bfr[j], acc[i][j], 0, 0, 0);
    }
  }
}

// ---------------------------------------------------------------------------
// Dual-B mainloop: one staged A-tile feeds TWO B-tiles (32 MFMA per K-step
// against 1.5x staging) — raises MFMA:stall ratio ~2x vs two separate kernels.
// ---------------------------------------------------------------------------
__device__ __forceinline__ void gemm_mainloop2(
    const ushort* __restrict__ A, int lda,
    const ushort* __restrict__ B1, const ushort* __restrict__ B2, int ldb,
    int K, int row0, int col0,
    ushort* Asm, ushort* B1sm, ushort* B2sm,
    f32x4 acc1[4][4], f32x4 acc2[4][4])
{
  const int tid  = threadIdx.x;
  const int wid  = tid >> 6;
  const int lane = tid & 63;
  const int l16  = lane & 15, lhi = lane >> 4;
  const int wm   = (wid >> 1) * 64, wn = (wid & 1) * 64;
  const int nk   = K >> 6;

  for (int kt = 0; kt < nk; ++kt) {
    __syncthreads();
    #pragma unroll
    for (int q = 0; q < 4; ++q) {
      int ee = q * 256 + tid;
      int r = ee >> 3, c = (ee & 7) << 3;
      GLDS(A  + (size_t)(row0 + r) * lda + (size_t)kt * 64 + c,
           (char*)Asm  + (q * 4096 + wid * 1024));
      GLDS(B1 + (size_t)(col0 + r) * ldb + (size_t)kt * 64 + c,
           (char*)B1sm + (q * 4096 + wid * 1024));
      GLDS(B2 + (size_t)(col0 + r) * ldb + (size_t)kt * 64 + c,
           (char*)B2sm + (q * 4096 + wid * 1024));
    }
    __syncthreads();
    #pragma unroll
    for (int kk = 0; kk < 2; ++kk) {
      bf16x8 af[4], b1f[4], b2f[4];
      #pragma unroll
      for (int i = 0; i < 4; ++i) {
        af[i]  = *(const bf16x8*)(Asm  + (wm + i * 16 + l16) * 64 + kk * 32 + lhi * 8);
        b1f[i] = *(const bf16x8*)(B1sm + (wn + i * 16 + l16) * 64 + kk * 32 + lhi * 8);
        b2f[i] = *(const bf16x8*)(B2sm + (wn + i * 16 + l16) * 64 + kk * 32 + lhi * 8);
      }
      #pragma unroll
      for (int i = 0; i < 4; ++i)
        #pragma unroll
        for (int j = 0; j < 4; ++j) {
          acc1[i][j] = __builtin_amdgcn_mfma_f32_16x16x32_bf16(af[i], b1f[j], acc1[i][j], 0, 0, 0);
          acc2[i][j] = __builtin_amdgcn_mfma_f32_16x16x32_bf16(af[i], b2f[j], acc2[i][j], 0, 0, 0);
        }
    }
  }
}

// ---------------------------------------------------------------------------
// Weight conversion: generic f32 [R][C] -> bf16 [Cpad][Rpad] (B^T), zero pad.
// ---------------------------------------------------------------------------
__global__ void transpose_cvt_kernel(const float* __restrict__ in, ushort* __restrict__ out,
                                     int R, int C, int Rpad, int Cpad)
{
  __shared__ float tile[32][33];
  int r0 = blockIdx.y * 32, c0 = blockIdx.x * 32;
  int tx = threadIdx.x, ty = threadIdx.y;
  #pragma unroll
  for (int i = 0; i < 32; i += 8) {
    int r = r0 + ty + i, c = c0 + tx;
    tile[ty + i][tx] = (r < R && c < C) ? in[(size_t)r * C + c] : 0.f;
  }
  __syncthreads();
  #pragma unroll
  for (int i = 0; i < 32; i += 8) {
    int cc = c0 + ty + i, rr = r0 + tx;
    if (cc < Cpad && rr < Rpad)
      out[(size_t)cc * Rpad + rr] = f2bf(tile[tx][ty + i]);
  }
}

struct Ptr8 { const float* p[8]; };

__global__ void gate_wcvt_kernel(Ptr8 src, ushort* __restrict__ out)
{
  __shared__ float tile[32][33];
  int tz = blockIdx.z;                 // 0..63
  int tensor = tz >> 3, h = tz & 7;
  const float* in = src.p[tensor] + (size_t)h * HSn * HSn;
  ushort* o = out + (size_t)tz * HSn * HSn;
  int r0 = blockIdx.y * 32, c0 = blockIdx.x * 32;
  int tx = threadIdx.x, ty = threadIdx.y;
  #pragma unroll
  for (int i = 0; i < 32; i += 8)
    tile[ty + i][tx] = in[(size_t)(r0 + ty + i) * HSn + c0 + tx];
  __syncthreads();
  #pragma unroll
  for (int i = 0; i < 32; i += 8)
    o[(size_t)(c0 + ty + i) * HSn + (r0 + tx)] = f2bf(tile[tx][ty + i]);
}

__global__ void cvt_bf16_kernel(const float* __restrict__ in, ushort* __restrict__ out, int n8)
{
  int idx = blockIdx.x * blockDim.x + threadIdx.x;
  if (idx >= n8) return;
  float4 a = ((const float4*)in)[idx * 2];
  float4 b = ((const float4*)in)[idx * 2 + 1];
  bf16x8 v;
  v[0] = (short)f2bf(a.x); v[1] = (short)f2bf(a.y);
  v[2] = (short)f2bf(a.z); v[3] = (short)f2bf(a.w);
  v[4] = (short)f2bf(b.x); v[5] = (short)f2bf(b.y);
  v[6] = (short)f2bf(b.z); v[7] = (short)f2bf(b.w);
  ((bf16x8*)out)[idx] = v;
}

// ---------------------------------------------------------------------------
// LayerNorm + causal conv1d(k=4) + SiLU, per row. Emits x (bf16) and x_conv (bf16).
// ---------------------------------------------------------------------------
__global__ __launch_bounds__(256) void ln_conv_kernel(
    const float* __restrict__ x, const float* __restrict__ lnw, const float* __restrict__ lnb,
    const float* __restrict__ convw, const float* __restrict__ convb,
    ushort* __restrict__ xbf, ushort* __restrict__ xcbf)
{
  __shared__ float xn[Dn];
  __shared__ float red[8];
  const int b = blockIdx.x, t = threadIdx.x;
  const float* xr = x + (size_t)b * Dn;
  float4 v0 = ((const float4*)xr)[t * 2];
  float4 v1 = ((const float4*)xr)[t * 2 + 1];
  float xv[8] = {v0.x, v0.y, v0.z, v0.w, v1.x, v1.y, v1.z, v1.w};
  float s = 0.f, s2 = 0.f;
  #pragma unroll
  for (int e = 0; e < 8; ++e) { s += xv[e]; s2 += xv[e] * xv[e]; }
  #pragma unroll
  for (int off = 32; off >= 1; off >>= 1) {
    s  += __shfl_xor(s, off, 64);
    s2 += __shfl_xor(s2, off, 64);
  }
  int wid = t >> 6;
  if ((t & 63) == 0) { red[wid] = s; red[4 + wid] = s2; }
  __syncthreads();
  s  = red[0] + red[1] + red[2] + red[3];
  s2 = red[4] + red[5] + red[6] + red[7];
  float mean = s * (1.f / Dn);
  float var  = s2 * (1.f / Dn) - mean * mean;
  float rstd = rsqrtf(var + EPSn);

  float4 w0 = ((const float4*)lnw)[t * 2], w1 = ((const float4*)lnw)[t * 2 + 1];
  float4 b0 = ((const float4*)lnb)[t * 2], b1 = ((const float4*)lnb)[t * 2 + 1];
  float lw[8] = {w0.x, w0.y, w0.z, w0.w, w1.x, w1.y, w1.z, w1.w};
  float lb[8] = {b0.x, b0.y, b0.z, b0.w, b1.x, b1.y, b1.z, b1.w};
  bf16x8 xb;
  #pragma unroll
  for (int e = 0; e < 8; ++e) {
    int j = t * 8 + e;
    float nv = (xv[e] - mean) * rstd * lw[e] + lb[e];
    xn[j] = nv;
    xb[e] = (short)f2bf(xv[e]);
  }
  ((bf16x8*)(xbf + (size_t)b * Dn))[t] = xb;
  __syncthreads();
  float w[4] = {convw[0], convw[1], convw[2], convw[3]};
  float cb = convb[0];
  bf16x8 cv;
  #pragma unroll
  for (int e = 0; e < 8; ++e) {
    int j = t * 8 + e;
    float a0 = (j >= 3) ? xn[j - 3] : 0.f;
    float a1 = (j >= 2) ? xn[j - 2] : 0.f;
    float a2 = (j >= 1) ? xn[j - 1] : 0.f;
    float v = w[0] * a0 + w[1] * a1 + w[2] * a2 + w[3] * xn[j] + cb;
    float sv = v / (1.f + expf(-v));
    cv[e] = (short)f2bf(sv);
  }
  ((bf16x8*)(xcbf + (size_t)b * Dn))[t] = cv;
}

// ---------------------------------------------------------------------------
// Gate GEMMs, PAIR-FUSED: grid (64 tiles, 8 heads, 2 pairs).
// pair 0 = {z (tanh), o (sigmoid)} share A = x, h_prev.
// pair 1 = {i (raw),  f (raw)}     share A = x_conv, h_prev.
// ---------------------------------------------------------------------------
struct GateArgs { const float* wb[4]; const float* rb[4]; };

__global__ __launch_bounds__(256, 2) void gate_gemm_kernel(
    const ushort* __restrict__ xbf, const ushort* __restrict__ xcbf,
    const ushort* __restrict__ hbf, const ushort* __restrict__ gWt,
    GateArgs gb, float* __restrict__ preact)
{
  __shared__ ushort Asm[128 * 64], B1sm[128 * 64], B2sm[128 * 64];
  const int p = blockIdx.z, h = blockIdx.y;
  const int gA = (p == 0) ? 0 : 1;             // z or i
  const int gB = (p == 0) ? 3 : 2;             // o or f
  const int bx = xcd_swz(blockIdx.x, 64);
  const int mt = bx >> 1, nt = bx & 1;
  const int row0 = mt * 128, col0 = nt * 128;
  f32x4 accA[4][4], accB[4][4];
  #pragma unroll
  for (int i = 0; i < 4; ++i)
    #pragma unroll
    for (int j = 0; j < 4; ++j) { accA[i][j] = f32x4{0.f,0.f,0.f,0.f}; accB[i][j] = f32x4{0.f,0.f,0.f,0.f}; }

  const ushort* A1 = ((p == 0) ? xbf : xcbf) + h * HSn;
  gemm_mainloop2(A1, Dn,
                 gWt + (size_t)(gA * 8 + h) * (HSn * HSn),
                 gWt + (size_t)(gB * 8 + h) * (HSn * HSn), HSn,
                 HSn, row0, col0, Asm, B1sm, B2sm, accA, accB);
  const ushort* A2 = hbf + h * HSn;
  gemm_mainloop2(A2, Dn,
                 gWt + (size_t)((4 + gA) * 8 + h) * (HSn * HSn),
                 gWt + (size_t)((4 + gB) * 8 + h) * (HSn * HSn), HSn,
                 HSn, row0, col0, Asm, B1sm, B2sm, accA, accB);

  const int tid = threadIdx.x, wid = tid >> 6, lane = tid & 63;
  const int l16 = lane & 15, lhi = lane >> 4;
  const int wm = (wid >> 1) * 64, wn = (wid & 1) * 64;
  const size_t NE = (size_t)Bn * Dn;
  float* outA = preact + (size_t)gA * NE;
  float* outB = preact + (size_t)gB * NE;
  const float* wbA = gb.wb[gA] + h * HSn;  const float* rbA = gb.rb[gA] + h * HSn;
  const float* wbB = gb.wb[gB] + h * HSn;  const float* rbB = gb.rb[gB] + h * HSn;
  #pragma unroll
  for (int j = 0; j < 4; ++j) {
    int cg = col0 + wn + j * 16 + l16;
    float biasA = wbA[cg] + rbA[cg];
    float biasB = wbB[cg] + rbB[cg];
    #pragma unroll
    for (int i = 0; i < 4; ++i) {
      #pragma unroll
      for (int r = 0; r < 4; ++r) {
        int rg = row0 + wm + i * 16 + lhi * 4 + r;
        float vA = accA[i][j][r] + biasA;
        float vB = accB[i][j][r] + biasB;
        if (p == 0) { vA = tanhf(vA); vB = 1.f / (1.f + expf(-vB)); }
        size_t idx = (size_t)rg * Dn + h * HSn + cg;
        outA[idx] = vA;
        outB[idx] = vB;
      }
    }
  }
}

// ---------------------------------------------------------------------------
// exp-gating pointwise + GroupNorm(8 groups of 256). 1 wave per (b, head).
// ---------------------------------------------------------------------------
__global__ __launch_bounds__(64) void gate_pw_gn_kernel(
    const float* __restrict__ preact,
    const float* __restrict__ c_prev, const float* __restrict__ n_prev,
    const float* __restrict__ m_prev,
    const float* __restrict__ gn_w, const float* __restrict__ gn_b,
    float* __restrict__ o_h, float* __restrict__ o_c,
    float* __restrict__ o_n, float* __restrict__ o_m,
    ushort* __restrict__ gnbf)
{
  const int bh = blockIdx.x;
  const int b = bh >> 3, h = bh & 7;
  const int t = threadIdx.x;
  const size_t NE = (size_t)Bn * Dn;
  const size_t base = (size_t)b * Dn + h * HSn + t * 4;

  float4 z4 = *(const float4*)(preact + base);
  float4 i4 = *(const float4*)(preact + NE + base);
  float4 f4 = *(const float4*)(preact + 2 * NE + base);
  float4 o4 = *(const float4*)(preact + 3 * NE + base);
  float4 c4 = *(const float4*)(c_prev + base);
  float4 n4 = *(const float4*)(n_prev + base);
  float4 m4 = *(const float4*)(m_prev + base);

  float za[4] = {z4.x, z4.y, z4.z, z4.w};
  float ia[4] = {i4.x, i4.y, i4.z, i4.w};
  float fa[4] = {f4.x, f4.y, f4.z, f4.w};
  float oa[4] = {o4.x, o4.y, o4.z, o4.w};
  float ca[4] = {c4.x, c4.y, c4.z, c4.w};
  float na[4] = {n4.x, n4.y, n4.z, n4.w};
  float ma[4] = {m4.x, m4.y, m4.z, m4.w};

  float hv[4], mo[4], co[4], no[4];
  float s = 0.f, s2 = 0.f;
  #pragma unroll
  for (int e = 0; e < 4; ++e) {
    float mt = fmaxf(fa[e] + ma[e], ia[e]);
    float ig = expf(ia[e] - mt);
    float fg = expf(fa[e] + ma[e] - mt);
    float ct = fg * ca[e] + ig * za[e];
    float nt = fg * na[e] + ig;
    float ht = oa[e] * ct / nt;
    mo[e] = mt; co[e] = ct; no[e] = nt; hv[e] = ht;
    s += ht; s2 += ht * ht;
  }
  *(float4*)(o_m + base) = make_float4(mo[0], mo[1], mo[2], mo[3]);
  *(float4*)(o_c + base) = make_float4(co[0], co[1], co[2], co[3]);
  *(float4*)(o_n + base) = make_float4(no[0], no[1], no[2], no[3]);
  *(float4*)(o_h + base) = make_float4(hv[0], hv[1], hv[2], hv[3]);

  #pragma unroll
  for (int off = 32; off >= 1; off >>= 1) {
    s  += __shfl_xor(s, off, 64);
    s2 += __shfl_xor(s2, off, 64);
  }
  float mean = s * (1.f / HSn);
  float var  = s2 * (1.f / HSn) - mean * mean;
  float rstd = rsqrtf(var + EPSn);
  u16x4 gv;
  #pragma unroll
  for (int e = 0; e < 4; ++e) {
    int hid = h * HSn + t * 4 + e;
    float gval = (hv[e] - mean) * rstd * gn_w[hid] + gn_b[hid];
    gv[e] = f2bf(gval);
  }
  *(u16x4*)(gnbf + base) = gv;
}

// ---------------------------------------------------------------------------
// FUSED up GEMM: C_L and C_R computed together; epilogue writes
// act = (C_L + bL) * gelu(C_R + bR) as bf16. No leftbuf round-trip.
// ---------------------------------------------------------------------------
__global__ __launch_bounds__(256, 2) void up_fused_kernel(
    const ushort* __restrict__ gnbf,
    const ushort* __restrict__ upLt, const ushort* __restrict__ upRt,
    const float* __restrict__ upLb, const float* __restrict__ upRb,
    ushort* __restrict__ actbf)
{
  __shared__ ushort Asm[128 * 64], B1sm[128 * 64], B2sm[128 * 64];
  const int NT = PPADn / 128;                  // 22
  const int bx = xcd_swz(blockIdx.x, 32 * NT);
  const int mt = bx / NT, nt = bx % NT;
  const int row0 = mt * 128, col0 = nt * 128;
  f32x4 accL[4][4], accR[4][4];
  #pragma unroll
  for (int i = 0; i < 4; ++i)
    #pragma unroll
    for (int j = 0; j < 4; ++j) { accL[i][j] = f32x4{0.f,0.f,0.f,0.f}; accR[i][j] = f32x4{0.f,0.f,0.f,0.f}; }

  gemm_mainloop2(gnbf, Dn, upLt, upRt, Dn, Dn, row0, col0,
                 Asm, B1sm, B2sm, accL, accR);

  const int tid = threadIdx.x, wid = tid >> 6, lane = tid & 63;
  const int l16 = lane & 15, lhi = lane >> 4;
  const int wm = (wid >> 1) * 64, wn = (wid & 1) * 64;
  #pragma unroll
  for (int j = 0; j < 4; ++j) {
    int col = col0 + wn + j * 16 + l16;
    float bL = (col < Pn) ? upLb[col] : 0.f;
    float bR = (col < Pn) ? upRb[col] : 0.f;
    #pragma unroll
    for (int i = 0; i < 4; ++i) {
      #pragma unroll
      for (int r = 0; r < 4; ++r) {
        int rg = row0 + wm + i * 16 + lhi * 4 + r;
        float lv = accL[i][j][r] + bL;
        float rv = accR[i][j][r] + bR;
        float ge = 0.5f * rv * (1.f + erff(rv * 0.70710678118f));
        actbf[(size_t)rg * PPADn + col] = f2bf(lv * ge);
      }
    }
  }
}

// ---------------------------------------------------------------------------
// down GEMM: out = act @ down + bias + x
// ---------------------------------------------------------------------------
__global__ __launch_bounds__(256) void down_gemm_kernel(
    const ushort* __restrict__ actbf, const ushort* __restrict__ downt,
    const float* __restrict__ downb, const float* __restrict__ x,
    float* __restrict__ outp)
{
  __shared__ ushort Asm[128 * 64];
  __shared__ ushort Bsm[128 * 64];
  const int NT = Dn / 128;                     // 16
  const int bx = xcd_swz(blockIdx.x, 32 * NT);
  const int mt = bx / NT, nt = bx % NT;
  const int row0 = mt * 128, col0 = nt * 128;
  f32x4 acc[4][4];
  #pragma unroll
  for (int i = 0; i < 4; ++i)
    #pragma unroll
    for (int j = 0; j < 4; ++j) acc[i][j] = f32x4{0.f, 0.f, 0.f, 0.f};

  gemm_mainloop(actbf, PPADn, downt, PPADn, PPADn, row0, col0, Asm, Bsm, acc);

  const int tid = threadIdx.x, wid = tid >> 6, lane = tid & 63;
  const int l16 = lane & 15, lhi = lane >> 4;
  const int wm = (wid >> 1) * 64, wn = (wid & 1) * 64;
  #pragma unroll
  for (int j = 0; j < 4; ++j) {
    int col = col0 + wn + j * 16 + l16;
    float bias = downb[col];
    #pragma unroll
    for (int i = 0; i < 4; ++i) {
      #pragma unroll
      for (int r = 0; r < 4; ++r) {
        int rg = row0 + wm + i * 16 + lhi * 4 + r;
        size_t idx = (size_t)rg * Dn + col;
        outp[idx] = acc[i][j][r] + bias + x[idx];
      }
    }
  }
}

// ---------------------------------------------------------------------------
extern "C" void kernel_launch(void* const* d_in, const int* in_sizes, int n_in,
                              void* d_out, int out_size, void* d_ws, size_t ws_size,
                              hipStream_t stream)
{
  const float* x      = (const float*)d_in[0];
  const float* h_prev = (const float*)d_in[1];
  const float* c_prev = (const float*)d_in[2];
  const float* n_prev = (const float*)d_in[3];
  const float* m_prev = (const float*)d_in[4];
  const float* ln_w   = (const float*)d_in[5];
  const float* ln_b   = (const float*)d_in[6];
  const float* conv_w = (const float*)d_in[7];
  const float* conv_b = (const float*)d_in[8];
  const float* gn_w   = (const float*)d_in[9];
  const float* gn_b   = (const float*)d_in[10];
  const float* upL_b  = (const float*)d_in[12];
  const float* upR_b  = (const float*)d_in[14];
  const float* down_b = (const float*)d_in[16];

  const size_t NE = (size_t)Bn * Dn;

  // workspace layout. actbf ALIASES the preact region (preact fully consumed
  // by gate_pw_gn before up_fused writes actbf; stream order serializes).
  char* ws = (char*)d_ws;
  size_t off = 0;
  auto alloc = [&](size_t bytes) { void* p = ws + off; off += (bytes + 255) & ~(size_t)255; return p; };
  ushort* xbf   = (ushort*)alloc(NE * 2);
  ushort* xcbf  = (ushort*)alloc(NE * 2);
  ushort* hbf   = (ushort*)alloc(NE * 2);
  ushort* gnbf  = (ushort*)alloc(NE * 2);
  ushort* gWt   = (ushort*)alloc((size_t)8 * Hn * HSn * HSn * 2);
  ushort* upLt  = (ushort*)alloc((size_t)PPADn * Dn * 2);
  ushort* upRt  = (ushort*)alloc((size_t)PPADn * Dn * 2);
  ushort* downt = (ushort*)alloc((size_t)Dn * PPADn * 2);
  float*  preact  = (float*)alloc(4 * NE * 4);          // 128 MB
  ushort* actbf   = (ushort*)preact;                    // 23 MB (alias)
  (void)ws_size; (void)in_sizes; (void)n_in; (void)out_size;

  float* out = (float*)d_out;
  float* o_out = out;
  float* o_h = out + NE;
  float* o_c = out + 2 * NE;
  float* o_n = out + 3 * NE;
  float* o_m = out + 4 * NE;

  // 1. gate weight transpose-convert (8 tensors x 8 heads)
  Ptr8 src;
  src.p[0] = (const float*)d_in[17]; src.p[1] = (const float*)d_in[19];
  src.p[2] = (const float*)d_in[21]; src.p[3] = (const float*)d_in[23];
  src.p[4] = (const float*)d_in[25]; src.p[5] = (const float*)d_in[27];
  src.p[6] = (const float*)d_in[29]; src.p[7] = (const float*)d_in[31];
  gate_wcvt_kernel<<<dim3(8, 8, 64), dim3(32, 8), 0, stream>>>(src, gWt);

  // 2. MLP weight transposes (B^T layout, P padded to 2816 with zeros)
  transpose_cvt_kernel<<<dim3(PPADn / 32, Dn / 32), dim3(32, 8), 0, stream>>>(
      (const float*)d_in[11], upLt, Dn, Pn, Dn, PPADn);
  transpose_cvt_kernel<<<dim3(PPADn / 32, Dn / 32), dim3(32, 8), 0, stream>>>(
      (const float*)d_in[13], upRt, Dn, Pn, Dn, PPADn);
  transpose_cvt_kernel<<<dim3(Dn / 32, PPADn / 32), dim3(32, 8), 0, stream>>>(
      (const float*)d_in[15], downt, Pn, Dn, PPADn, Dn);

  // 3. h_prev -> bf16
  cvt_bf16_kernel<<<(int)(NE / 8 / 256), 256, 0, stream>>>(h_prev, hbf, (int)(NE / 8));

  // 4. LayerNorm + conv + silu (also emits x as bf16)
  ln_conv_kernel<<<Bn, 256, 0, stream>>>(x, ln_w, ln_b, conv_w, conv_b, xbf, xcbf);

  // 5. gate GEMMs (pair-fused: {z,o} and {i,f})
  GateArgs ga;
  ga.wb[0] = (const float*)d_in[18]; ga.wb[1] = (const float*)d_in[20];
  ga.wb[2] = (const float*)d_in[22]; ga.wb[3] = (const float*)d_in[24];
  ga.rb[0] = (const float*)d_in[26]; ga.rb[1] = (const float*)d_in[28];
  ga.rb[2] = (const float*)d_in[30]; ga.rb[3] = (const float*)d_in[32];
  gate_gemm_kernel<<<dim3(64, 8, 2), 256, 0, stream>>>(xbf, xcbf, hbf, gWt, ga, preact);

  // 6. gating pointwise + GroupNorm
  gate_pw_gn_kernel<<<Bn * Hn, 64, 0, stream>>>(preact, c_prev, n_prev, m_prev,
                                                gn_w, gn_b, o_h, o_c, o_n, o_m, gnbf);

  // 7. fused up GEMM (left*gelu(right) -> bf16 act, no leftbuf)
  up_fused_kernel<<<32 * (PPADn / 128), 256, 0, stream>>>(gnbf, upLt, upRt,
                                                          upL_b, upR_b, actbf);

  // 8. down GEMM + bias + residual
  down_gemm_kernel<<<32 * (Dn / 128), 256, 0, stream>>>(actbf, downt, down_b, x, o_out);
}